// Round 1
// baseline (190.725 us; speedup 1.0000x reference)
//
#include <hip/hip_runtime.h>
#include <math.h>

// DSVF biquad IIR, scipy.signal.lfilter semantics (direct form II transposed),
// B=512 rows, T=32768 samples. Chunked linear-scan parallelization:
//   state s=(z1,z2): s_t = M s_{t-1} + v*x_t, M=[[-a1,1],[-a2,0]]
//   chunk(L): s_end = M^L s_init + d  (d = zero-init chunk result)
// K1: per-chunk d_k (zero init).  K2: per-row scan with M^L (f64).
// K3: rerun chunks with true init states, emit y.

namespace {
constexpr int kB = 512;
constexpr int kT = 32768;
constexpr int kChunk = 128;            // samples per chunk
constexpr int kNChunk = kT / kChunk;   // 256 chunks per row
constexpr int kLog2Chunk = 7;          // kChunk == 2^7
}

__device__ inline void coeffs_f64(const float* g, const float* r,
                                  const float* mhp_, const float* mbp_,
                                  const float* mlp_,
                                  double& b0, double& b1, double& b2,
                                  double& a1, double& a2) {
  double graw = (double)g[0];
  double rraw = (double)r[0];
  double mhp = (double)mhp_[0], mbp = (double)mbp_[0], mlp = (double)mlp_[0];
  double sig = 1.0 / (1.0 + exp(-graw));
  double gg = tan(1.5707963267948966 * sig);          // tan(pi*sigmoid/2)
  double rr = (rraw > 30.0) ? rraw : log1p(exp(rraw)); // softplus
  double g2 = gg * gg;
  double B0 = g2 * mlp + gg * mbp + mhp;
  double B1 = 2.0 * g2 * mlp - 2.0 * mhp;
  double B2 = g2 * mlp - gg * mbp + mhp;
  double A0 = g2 + 2.0 * rr * gg + 1.0;
  double A1 = 2.0 * g2 - 2.0;
  double A2 = g2 - 2.0 * rr * gg + 1.0;
  double inv = 1.0 / A0;
  b0 = B0 * inv; b1 = B1 * inv; b2 = B2 * inv;
  a1 = A1 * inv; a2 = A2 * inv;
}

// --- K1: per-chunk zero-init final states -------------------------------
__global__ __launch_bounds__(256) void k_partial(
    const float* __restrict__ x, const float* g, const float* r,
    const float* mhp, const float* mbp, const float* mlp,
    float2* __restrict__ st) {
  int tid = blockIdx.x * 256 + threadIdx.x;
  int row = tid >> 8;                 // kNChunk == 256
  int chunk = tid & (kNChunk - 1);

  double db0, db1, db2, da1, da2;
  coeffs_f64(g, r, mhp, mbp, mlp, db0, db1, db2, da1, da2);
  float b0 = (float)db0, b1 = (float)db1, b2 = (float)db2;
  float na1 = (float)(-da1), na2 = (float)(-da2);

  const float4* xv =
      (const float4*)(x + (size_t)row * kT + (size_t)chunk * kChunk);
  float z1 = 0.f, z2 = 0.f;
#pragma unroll 8
  for (int i = 0; i < kChunk / 4; ++i) {
    float4 v = xv[i];
    float y;
    y = fmaf(b0, v.x, z1); z1 = fmaf(na1, y, fmaf(b1, v.x, z2)); z2 = fmaf(na2, y, b2 * v.x);
    y = fmaf(b0, v.y, z1); z1 = fmaf(na1, y, fmaf(b1, v.y, z2)); z2 = fmaf(na2, y, b2 * v.y);
    y = fmaf(b0, v.z, z1); z1 = fmaf(na1, y, fmaf(b1, v.z, z2)); z2 = fmaf(na2, y, b2 * v.z);
    y = fmaf(b0, v.w, z1); z1 = fmaf(na1, y, fmaf(b1, v.w, z2)); z2 = fmaf(na2, y, b2 * v.w);
  }
  st[(size_t)row * kNChunk + chunk] = make_float2(z1, z2);
}

// --- K2: per-row sequential scan over chunks (f64 for stability) --------
__global__ __launch_bounds__(256) void k_scan(
    float2* __restrict__ st, const float* g, const float* r,
    const float* mhp, const float* mbp, const float* mlp) {
  int row = blockIdx.x * 256 + threadIdx.x;
  if (row >= kB) return;

  double db0, db1, db2, da1, da2;
  coeffs_f64(g, r, mhp, mbp, mlp, db0, db1, db2, da1, da2);

  // M = [[-a1, 1], [-a2, 0]]; compute P = M^kChunk by repeated squaring.
  double m00 = -da1, m01 = 1.0, m10 = -da2, m11 = 0.0;
  for (int i = 0; i < kLog2Chunk; ++i) {
    double t00 = m00 * m00 + m01 * m10;
    double t01 = m00 * m01 + m01 * m11;
    double t10 = m10 * m00 + m11 * m10;
    double t11 = m10 * m01 + m11 * m11;
    m00 = t00; m01 = t01; m10 = t10; m11 = t11;
  }

  float2* rowp = st + (size_t)row * kNChunk;
  double s1 = 0.0, s2 = 0.0;
  for (int k = 0; k < kNChunk; ++k) {
    float2 dk = rowp[k];
    rowp[k] = make_float2((float)s1, (float)s2);  // init state for chunk k
    double n1 = m00 * s1 + m01 * s2 + (double)dk.x;
    double n2 = m10 * s1 + m11 * s2 + (double)dk.y;
    s1 = n1; s2 = n2;
  }
}

// --- K3: rerun chunks with true initial states, write y -----------------
__global__ __launch_bounds__(256) void k_final(
    const float* __restrict__ x, const float2* __restrict__ st,
    const float* g, const float* r, const float* mhp, const float* mbp,
    const float* mlp, float* __restrict__ out) {
  int tid = blockIdx.x * 256 + threadIdx.x;
  int row = tid >> 8;
  int chunk = tid & (kNChunk - 1);

  double db0, db1, db2, da1, da2;
  coeffs_f64(g, r, mhp, mbp, mlp, db0, db1, db2, da1, da2);
  float b0 = (float)db0, b1 = (float)db1, b2 = (float)db2;
  float na1 = (float)(-da1), na2 = (float)(-da2);

  float2 s0 = st[(size_t)row * kNChunk + chunk];
  float z1 = s0.x, z2 = s0.y;

  const float4* xv =
      (const float4*)(x + (size_t)row * kT + (size_t)chunk * kChunk);
  float4* yv = (float4*)(out + (size_t)row * kT + (size_t)chunk * kChunk);
#pragma unroll 8
  for (int i = 0; i < kChunk / 4; ++i) {
    float4 v = xv[i];
    float4 o;
    o.x = fmaf(b0, v.x, z1); z1 = fmaf(na1, o.x, fmaf(b1, v.x, z2)); z2 = fmaf(na2, o.x, b2 * v.x);
    o.y = fmaf(b0, v.y, z1); z1 = fmaf(na1, o.y, fmaf(b1, v.y, z2)); z2 = fmaf(na2, o.y, b2 * v.y);
    o.z = fmaf(b0, v.z, z1); z1 = fmaf(na1, o.z, fmaf(b1, v.z, z2)); z2 = fmaf(na2, o.z, b2 * v.z);
    o.w = fmaf(b0, v.w, z1); z1 = fmaf(na1, o.w, fmaf(b1, v.w, z2)); z2 = fmaf(na2, o.w, b2 * v.w);
    yv[i] = o;
  }
}

extern "C" void kernel_launch(void* const* d_in, const int* in_sizes, int n_in,
                              void* d_out, int out_size, void* d_ws,
                              size_t ws_size, hipStream_t stream) {
  const float* x   = (const float*)d_in[0];
  const float* g   = (const float*)d_in[1];
  const float* r   = (const float*)d_in[2];
  const float* mhp = (const float*)d_in[3];
  const float* mbp = (const float*)d_in[4];
  const float* mlp = (const float*)d_in[5];
  float* out = (float*)d_out;
  float2* st = (float2*)d_ws;  // kB * kNChunk float2 = 1 MiB

  const int nthreads = kB * kNChunk;  // 131072
  k_partial<<<nthreads / 256, 256, 0, stream>>>(x, g, r, mhp, mbp, mlp, st);
  k_scan<<<(kB + 255) / 256, 256, 0, stream>>>(st, g, r, mhp, mbp, mlp);
  k_final<<<nthreads / 256, 256, 0, stream>>>(x, st, g, r, mhp, mbp, mlp, out);
}

// Round 2
// 157.625 us; speedup vs baseline: 1.2100x; 1.2100x over previous
//
#include <hip/hip_runtime.h>
#include <math.h>

// DSVF biquad IIR (scipy lfilter DF2T), B=512, T=32768.
// Chunked linear-scan: s_t = M s_{t-1} + v x_t, M=[[-a1,1],[-a2,0]].
// k_coef: 1 thread, f64 coeffs + P=M^64 into ws.
// k_partial: per-chunk (64 samples) zero-init final states d_k.
// k_scan: per-row Kogge-Stone scan over 512 chunks (f64, LDS), writes init states.
// k_final: rerun chunks with true init states, emit y.

namespace {
constexpr int kB = 512;
constexpr int kT = 32768;
constexpr int kChunk = 64;                  // samples per chunk
constexpr int kNChunk = kT / kChunk;        // 512 chunks per row
constexpr int kVec = kChunk / 4;            // 16 float4 per chunk
constexpr int kScanThreads = 256;           // 2 chunks per thread in k_scan
}

struct CoefBlock {
  double p00, p01, p10, p11;    // P = M^kChunk (f64)
  float b0, b1, b2, na1, na2;   // f32 coeffs (na = -a)
  float pad[3];
};

__global__ void k_coef(const float* g, const float* r, const float* mhp,
                       const float* mbp, const float* mlp,
                       CoefBlock* __restrict__ cb) {
  double graw = (double)g[0], rraw = (double)r[0];
  double m_hp = (double)mhp[0], m_bp = (double)mbp[0], m_lp = (double)mlp[0];
  double sig = 1.0 / (1.0 + exp(-graw));
  double gg = tan(1.5707963267948966 * sig);           // tan(pi*sigmoid/2)
  double rr = (rraw > 30.0) ? rraw : log1p(exp(rraw)); // softplus
  double g2 = gg * gg;
  double B0 = g2 * m_lp + gg * m_bp + m_hp;
  double B1 = 2.0 * g2 * m_lp - 2.0 * m_hp;
  double B2 = g2 * m_lp - gg * m_bp + m_hp;
  double A0 = g2 + 2.0 * rr * gg + 1.0;
  double A1 = 2.0 * g2 - 2.0;
  double A2 = g2 - 2.0 * rr * gg + 1.0;
  double inv = 1.0 / A0;
  double b0 = B0 * inv, b1 = B1 * inv, b2 = B2 * inv;
  double a1 = A1 * inv, a2 = A2 * inv;
  // P = M^kChunk via 6 squarings (kChunk = 64).
  double m00 = -a1, m01 = 1.0, m10 = -a2, m11 = 0.0;
  for (int i = 0; i < 6; ++i) {
    double t00 = m00 * m00 + m01 * m10;
    double t01 = m00 * m01 + m01 * m11;
    double t10 = m10 * m00 + m11 * m10;
    double t11 = m10 * m01 + m11 * m11;
    m00 = t00; m01 = t01; m10 = t10; m11 = t11;
  }
  cb->p00 = m00; cb->p01 = m01; cb->p10 = m10; cb->p11 = m11;
  cb->b0 = (float)b0; cb->b1 = (float)b1; cb->b2 = (float)b2;
  cb->na1 = (float)(-a1); cb->na2 = (float)(-a2);
}

#define IIR_STEP(xx, yy)                                         \
  do {                                                           \
    yy = fmaf(b0, xx, z1);                                       \
    z1 = fmaf(na1, yy, fmaf(b1, xx, z2));                        \
    z2 = fmaf(na2, yy, b2 * xx);                                 \
  } while (0)

// --- K1: per-chunk zero-init final states -------------------------------
__global__ __launch_bounds__(256) void k_partial(
    const float* __restrict__ x, const CoefBlock* __restrict__ cb,
    float2* __restrict__ st) {
  int tid = blockIdx.x * 256 + threadIdx.x;
  int row = tid >> 9;                 // kNChunk == 512
  int chunk = tid & (kNChunk - 1);

  float b0 = cb->b0, b1 = cb->b1, b2 = cb->b2, na1 = cb->na1, na2 = cb->na2;

  const float4* xv =
      (const float4*)(x + (size_t)row * kT + (size_t)chunk * kChunk);
  float4 v[kVec];
#pragma unroll
  for (int i = 0; i < kVec; ++i) v[i] = xv[i];  // 16 loads in flight

  float z1 = 0.f, z2 = 0.f;
#pragma unroll
  for (int i = 0; i < kVec; ++i) {
    float y;
    IIR_STEP(v[i].x, y); IIR_STEP(v[i].y, y);
    IIR_STEP(v[i].z, y); IIR_STEP(v[i].w, y);
  }
  st[(size_t)row * kNChunk + chunk] = make_float2(z1, z2);
}

// --- K2: per-row Kogge-Stone scan over chunks (f64) ---------------------
__global__ __launch_bounds__(kScanThreads) void k_scan(
    float2* __restrict__ st, const CoefBlock* __restrict__ cb) {
  int row = blockIdx.x;
  int t = threadIdx.x;
  double p00 = cb->p00, p01 = cb->p01, p10 = cb->p10, p11 = cb->p11;

  float2* rowp = st + (size_t)row * kNChunk;
  float4 ld = ((const float4*)rowp)[t];       // d_{2t}, d_{2t+1}
  double d0x = (double)ld.x, d0y = (double)ld.y;
  double d1x = (double)ld.z, d1y = (double)ld.w;

  // Thread-local inclusive over its 2 chunks: A = d1 + P*d0; span matrix Q=P^2.
  double a1v = p00 * d0x + p01 * d0y + d1x;
  double a2v = p10 * d0x + p11 * d0y + d1y;
  double w00 = p00 * p00 + p01 * p10, w01 = p00 * p01 + p01 * p11;
  double w10 = p10 * p00 + p11 * p10, w11 = p10 * p01 + p11 * p11;

  __shared__ double s1[kScanThreads], s2[kScanThreads];
  for (int o = 1; o < kScanThreads; o <<= 1) {
    s1[t] = a1v; s2[t] = a2v;
    __syncthreads();
    double q1 = 0.0, q2 = 0.0;
    if (t >= o) { q1 = s1[t - o]; q2 = s2[t - o]; }
    __syncthreads();
    a1v += w00 * q1 + w01 * q2;
    a2v += w10 * q1 + w11 * q2;
    double t00 = w00 * w00 + w01 * w10, t01 = w00 * w01 + w01 * w11;
    double t10 = w10 * w00 + w11 * w10, t11 = w10 * w01 + w11 * w11;
    w00 = t00; w01 = t01; w10 = t10; w11 = t11;
  }
  // Exclusive prefix = init state before this thread's first chunk.
  s1[t] = a1v; s2[t] = a2v;
  __syncthreads();
  double e1 = 0.0, e2 = 0.0;
  if (t > 0) { e1 = s1[t - 1]; e2 = s2[t - 1]; }
  // chunk 2t init = E; chunk 2t+1 init = P*E + d0.
  double i1 = p00 * e1 + p01 * e2 + d0x;
  double i2 = p10 * e1 + p11 * e2 + d0y;
  ((float4*)rowp)[t] = make_float4((float)e1, (float)e2, (float)i1, (float)i2);
}

// --- K3: rerun chunks with true initial states, write y -----------------
__global__ __launch_bounds__(256) void k_final(
    const float* __restrict__ x, const float2* __restrict__ st,
    const CoefBlock* __restrict__ cb, float* __restrict__ out) {
  int tid = blockIdx.x * 256 + threadIdx.x;
  int row = tid >> 9;
  int chunk = tid & (kNChunk - 1);

  float b0 = cb->b0, b1 = cb->b1, b2 = cb->b2, na1 = cb->na1, na2 = cb->na2;

  float2 s0 = st[(size_t)row * kNChunk + chunk];
  float z1 = s0.x, z2 = s0.y;

  const float4* xv =
      (const float4*)(x + (size_t)row * kT + (size_t)chunk * kChunk);
  float4* yv = (float4*)(out + (size_t)row * kT + (size_t)chunk * kChunk);
  float4 v[kVec];
#pragma unroll
  for (int i = 0; i < kVec; ++i) v[i] = xv[i];

#pragma unroll
  for (int i = 0; i < kVec; ++i) {
    float4 o;
    IIR_STEP(v[i].x, o.x); IIR_STEP(v[i].y, o.y);
    IIR_STEP(v[i].z, o.z); IIR_STEP(v[i].w, o.w);
    yv[i] = o;
  }
}

extern "C" void kernel_launch(void* const* d_in, const int* in_sizes, int n_in,
                              void* d_out, int out_size, void* d_ws,
                              size_t ws_size, hipStream_t stream) {
  const float* x   = (const float*)d_in[0];
  const float* g   = (const float*)d_in[1];
  const float* r   = (const float*)d_in[2];
  const float* mhp = (const float*)d_in[3];
  const float* mbp = (const float*)d_in[4];
  const float* mlp = (const float*)d_in[5];
  float* out = (float*)d_out;

  CoefBlock* cb = (CoefBlock*)d_ws;
  float2* st = (float2*)((char*)d_ws + 256);  // kB*kNChunk float2 = 2 MiB

  const int nthreads = kB * kNChunk;  // 262144
  k_coef<<<1, 1, 0, stream>>>(g, r, mhp, mbp, mlp, cb);
  k_partial<<<nthreads / 256, 256, 0, stream>>>(x, cb, st);
  k_scan<<<kB, kScanThreads, 0, stream>>>(st, cb);
  k_final<<<nthreads / 256, 256, 0, stream>>>(x, st, cb, out);
}

// Round 3
// 135.491 us; speedup vs baseline: 1.4077x; 1.1634x over previous
//
#include <hip/hip_runtime.h>
#include <math.h>

// DSVF biquad IIR (scipy lfilter DF2T), B=512, T=32768.
// Chunked linear-scan: s_t = M s_{t-1} + v x_t, M=[[-a1,1],[-a2,0]].
// k_partial: per-chunk (64 samples) zero-init final states d_k.
//            LDS-transposed coalesced loads (1 wave/block, 64 chunks = 16 KB).
// k_scan:    per-row Kogge-Stone scan over 512 chunks (f64, LDS) -> init states.
// k_final:   rerun chunks with true init states, emit y via LDS-transposed
//            coalesced stores (kills the 1.5x write amplification seen in R2).
// Coeffs computed per-thread in f32 (matches the f32 JAX reference exactly).

namespace {
constexpr int kB = 512;
constexpr int kT = 32768;
constexpr int kChunk = 64;               // samples per chunk (one thread)
constexpr int kNChunk = kT / kChunk;     // 512 chunks per row
constexpr int kScanThreads = 256;        // 2 chunks per thread in k_scan
constexpr int kStride = kChunk + 1;      // LDS chunk stride: 65 words -> 2-way banks
}

__device__ inline void coeffs_f32(const float* g, const float* r,
                                  const float* mhp, const float* mbp,
                                  const float* mlp, float& b0, float& b1,
                                  float& b2, float& a1, float& a2) {
  float graw = g[0], rraw = r[0];
  float sig = 1.0f / (1.0f + expf(-graw));
  float gg = tanf(1.5707963267948966f * sig);            // tan(pi*sigmoid/2)
  float rr = (rraw > 20.0f) ? rraw : log1pf(expf(rraw)); // softplus
  float g2 = gg * gg;
  float m_hp = mhp[0], m_bp = mbp[0], m_lp = mlp[0];
  float B0 = g2 * m_lp + gg * m_bp + m_hp;
  float B1 = 2.0f * g2 * m_lp - 2.0f * m_hp;
  float B2 = g2 * m_lp - gg * m_bp + m_hp;
  float A0 = g2 + 2.0f * rr * gg + 1.0f;
  float A1 = 2.0f * g2 - 2.0f;
  float A2 = g2 - 2.0f * rr * gg + 1.0f;
  float inv = 1.0f / A0;
  b0 = B0 * inv; b1 = B1 * inv; b2 = B2 * inv;
  a1 = A1 * inv; a2 = A2 * inv;
}

#define IIR_STEP(xx, yy)                                         \
  do {                                                           \
    yy = fmaf(b0, xx, z1);                                       \
    z1 = fmaf(na1, yy, fmaf(b1, xx, z2));                        \
    z2 = fmaf(na2, yy, b2 * xx);                                 \
  } while (0)

// --- K1: per-chunk zero-init final states (coalesced via LDS) -----------
__global__ __launch_bounds__(64) void k_partial(
    const float* __restrict__ x, const float* g, const float* r,
    const float* mhp, const float* mbp, const float* mlp,
    float2* __restrict__ st) {
  __shared__ float buf[64 * kStride];
  int lane = threadIdx.x;

  float b0, b1, b2, a1, a2;
  coeffs_f32(g, r, mhp, mbp, mlp, b0, b1, b2, a1, a2);
  float na1 = -a1, na2 = -a2;

  const float4* xv = (const float4*)x + (size_t)blockIdx.x * 1024;
  float4 v[16];
#pragma unroll
  for (int i = 0; i < 16; ++i) v[i] = xv[i * 64 + lane];  // coalesced 1 KB/instr

  // scatter into LDS: chunk (f>>4), word 4*(f&15); stride 65 -> 2-way banks
#pragma unroll
  for (int i = 0; i < 16; ++i) {
    int f = i * 64 + lane;
    int base = (f >> 4) * kStride + ((f & 15) << 2);
    buf[base] = v[i].x; buf[base + 1] = v[i].y;
    buf[base + 2] = v[i].z; buf[base + 3] = v[i].w;
  }
  __syncthreads();
#pragma unroll
  for (int i = 0; i < 16; ++i) {  // lane reads its own chunk
    int base = lane * kStride + (i << 2);
    v[i] = make_float4(buf[base], buf[base + 1], buf[base + 2], buf[base + 3]);
  }

  float z1 = 0.f, z2 = 0.f;
#pragma unroll
  for (int i = 0; i < 16; ++i) {
    float y;
    IIR_STEP(v[i].x, y); IIR_STEP(v[i].y, y);
    IIR_STEP(v[i].z, y); IIR_STEP(v[i].w, y);
  }
  st[(size_t)blockIdx.x * 64 + lane] = make_float2(z1, z2);
}

// --- K2: per-row Kogge-Stone scan over chunks (f64) ---------------------
__global__ __launch_bounds__(kScanThreads) void k_scan(
    float2* __restrict__ st, const float* g, const float* r,
    const float* mhp, const float* mbp, const float* mlp) {
  int row = blockIdx.x;
  int t = threadIdx.x;

  float b0f, b1f, b2f, a1f, a2f;
  coeffs_f32(g, r, mhp, mbp, mlp, b0f, b1f, b2f, a1f, a2f);
  // P = M^kChunk via 6 squarings in f64.
  double m00 = -(double)a1f, m01 = 1.0, m10 = -(double)a2f, m11 = 0.0;
  for (int i = 0; i < 6; ++i) {
    double t00 = m00 * m00 + m01 * m10;
    double t01 = m00 * m01 + m01 * m11;
    double t10 = m10 * m00 + m11 * m10;
    double t11 = m10 * m01 + m11 * m11;
    m00 = t00; m01 = t01; m10 = t10; m11 = t11;
  }
  double p00 = m00, p01 = m01, p10 = m10, p11 = m11;

  float2* rowp = st + (size_t)row * kNChunk;
  float4 ld = ((const float4*)rowp)[t];  // d_{2t}, d_{2t+1}
  double d0x = (double)ld.x, d0y = (double)ld.y;
  double d1x = (double)ld.z, d1y = (double)ld.w;

  // Thread-local inclusive over its 2 chunks: A = d1 + P*d0; span Q = P^2.
  double a1v = p00 * d0x + p01 * d0y + d1x;
  double a2v = p10 * d0x + p11 * d0y + d1y;
  double w00 = p00 * p00 + p01 * p10, w01 = p00 * p01 + p01 * p11;
  double w10 = p10 * p00 + p11 * p10, w11 = p10 * p01 + p11 * p11;

  __shared__ double s1[kScanThreads], s2[kScanThreads];
  for (int o = 1; o < kScanThreads; o <<= 1) {
    s1[t] = a1v; s2[t] = a2v;
    __syncthreads();
    double q1 = 0.0, q2 = 0.0;
    if (t >= o) { q1 = s1[t - o]; q2 = s2[t - o]; }
    __syncthreads();
    a1v += w00 * q1 + w01 * q2;
    a2v += w10 * q1 + w11 * q2;
    double t00 = w00 * w00 + w01 * w10, t01 = w00 * w01 + w01 * w11;
    double t10 = w10 * w00 + w11 * w10, t11 = w10 * w01 + w11 * w11;
    w00 = t00; w01 = t01; w10 = t10; w11 = t11;
  }
  s1[t] = a1v; s2[t] = a2v;
  __syncthreads();
  double e1 = 0.0, e2 = 0.0;
  if (t > 0) { e1 = s1[t - 1]; e2 = s2[t - 1]; }
  // chunk 2t init = E; chunk 2t+1 init = P*E + d0.
  double i1 = p00 * e1 + p01 * e2 + d0x;
  double i2 = p10 * e1 + p11 * e2 + d0y;
  ((float4*)rowp)[t] = make_float4((float)e1, (float)e2, (float)i1, (float)i2);
}

// --- K3: rerun chunks with true init states, write y (coalesced) --------
__global__ __launch_bounds__(64) void k_final(
    const float* __restrict__ x, const float2* __restrict__ st,
    const float* g, const float* r, const float* mhp, const float* mbp,
    const float* mlp, float* __restrict__ out) {
  __shared__ float buf[64 * kStride];
  int lane = threadIdx.x;

  float b0, b1, b2, a1, a2;
  coeffs_f32(g, r, mhp, mbp, mlp, b0, b1, b2, a1, a2);
  float na1 = -a1, na2 = -a2;

  const float4* xv = (const float4*)x + (size_t)blockIdx.x * 1024;
  float4 v[16];
#pragma unroll
  for (int i = 0; i < 16; ++i) v[i] = xv[i * 64 + lane];

#pragma unroll
  for (int i = 0; i < 16; ++i) {
    int f = i * 64 + lane;
    int base = (f >> 4) * kStride + ((f & 15) << 2);
    buf[base] = v[i].x; buf[base + 1] = v[i].y;
    buf[base + 2] = v[i].z; buf[base + 3] = v[i].w;
  }
  __syncthreads();
#pragma unroll
  for (int i = 0; i < 16; ++i) {
    int base = lane * kStride + (i << 2);
    v[i] = make_float4(buf[base], buf[base + 1], buf[base + 2], buf[base + 3]);
  }

  float2 s0 = st[(size_t)blockIdx.x * 64 + lane];
  float z1 = s0.x, z2 = s0.y;
#pragma unroll
  for (int i = 0; i < 16; ++i) {
    float4 o;
    IIR_STEP(v[i].x, o.x); IIR_STEP(v[i].y, o.y);
    IIR_STEP(v[i].z, o.z); IIR_STEP(v[i].w, o.w);
    v[i] = o;
  }

  // lane writes its own chunk's y back to LDS (lane-local; no barrier needed
  // vs the reads above), then the wave stores the 16 KB region coalesced.
#pragma unroll
  for (int i = 0; i < 16; ++i) {
    int base = lane * kStride + (i << 2);
    buf[base] = v[i].x; buf[base + 1] = v[i].y;
    buf[base + 2] = v[i].z; buf[base + 3] = v[i].w;
  }
  __syncthreads();
  float4* yv = (float4*)out + (size_t)blockIdx.x * 1024;
#pragma unroll
  for (int i = 0; i < 16; ++i) {
    int f = i * 64 + lane;
    int base = (f >> 4) * kStride + ((f & 15) << 2);
    yv[f] = make_float4(buf[base], buf[base + 1], buf[base + 2], buf[base + 3]);
  }
}

extern "C" void kernel_launch(void* const* d_in, const int* in_sizes, int n_in,
                              void* d_out, int out_size, void* d_ws,
                              size_t ws_size, hipStream_t stream) {
  const float* x   = (const float*)d_in[0];
  const float* g   = (const float*)d_in[1];
  const float* r   = (const float*)d_in[2];
  const float* mhp = (const float*)d_in[3];
  const float* mbp = (const float*)d_in[4];
  const float* mlp = (const float*)d_in[5];
  float* out = (float*)d_out;
  float2* st = (float2*)d_ws;  // kB*kNChunk float2 = 2 MiB

  const int nblocks = kB * kNChunk / 64;  // 4096 wave-blocks
  k_partial<<<nblocks, 64, 0, stream>>>(x, g, r, mhp, mbp, mlp, st);
  k_scan<<<kB, kScanThreads, 0, stream>>>(st, g, r, mhp, mbp, mlp);
  k_final<<<nblocks, 64, 0, stream>>>(x, st, g, r, mhp, mbp, mlp, out);
}